// Round 9
// baseline (412.706 us; speedup 1.0000x reference)
//
#include <hip/hip_runtime.h>
#include <math.h>

#define DD 64      // per-head channels
#define HH 8       // heads
#define HD 512     // HH*DD
#define NC 1024    // combined xl|xr row width

typedef __attribute__((ext_vector_type(8))) short bf16x8;
typedef __attribute__((ext_vector_type(4))) float f32x4;

// ---------------------------------------------------------------------------
// bf16 split helpers (round-to-nearest-even)
// ---------------------------------------------------------------------------
__device__ __forceinline__ ushort bf16_rne(float f) {
    uint u = __float_as_uint(f);
    u += 0x7fffu + ((u >> 16) & 1u);
    return (ushort)(u >> 16);
}
__device__ __forceinline__ float bf16_tof(ushort h) {
    return __uint_as_float(((uint)h) << 16);
}

// elementwise fp32 -> (hi, lo) bf16 pair
__global__ __launch_bounds__(256) void split_mat(const float* __restrict__ in,
                                                 ushort* __restrict__ hi,
                                                 ushort* __restrict__ lo, int total)
{
    const int i = blockIdx.x * 256 + threadIdx.x;
    if (i >= total) return;
    const float f = in[i];
    const ushort h = bf16_rne(f);
    hi[i] = h;
    lo[i] = bf16_rne(f - bf16_tof(h));
}

// W0,W1: [K][512] fp32 -> Bt: [1024][K] bf16 hi/lo (transposed, concatenated)
__global__ __launch_bounds__(256) void split_wT(const float* __restrict__ W0,
                                                const float* __restrict__ W1,
                                                ushort* __restrict__ hi,
                                                ushort* __restrict__ lo, int kshift)
{
    const int K = 1 << kshift;
    const int i = blockIdx.x * 256 + threadIdx.x;    // i = c*K + k
    if (i >= 1024 * K) return;
    const int c = i >> kshift, k = i & (K - 1);
    const float* W = (c < 512) ? W0 : W1;
    const float f = W[(size_t)k * 512 + (c & 511)];
    const ushort h = bf16_rne(f);
    hi[i] = h;
    lo[i] = bf16_rne(f - bf16_tof(h));
}

// ---------------------------------------------------------------------------
// bf16x3 split-precision MFMA GEMM (unchanged from round 8).
// ---------------------------------------------------------------------------
__global__ __launch_bounds__(256) void gemm_bf16x3(
    const ushort* __restrict__ Ah, const ushort* __restrict__ Al,
    const ushort* __restrict__ Bh, const ushort* __restrict__ Bl,
    float* __restrict__ C, int M, int K)
{
    __shared__ __align__(16) ushort lAh[128 * 64];
    __shared__ __align__(16) ushort lAl[128 * 64];
    __shared__ __align__(16) ushort lBh[128 * 64];
    __shared__ __align__(16) ushort lBl[128 * 64];

    const int nwg = gridDim.x;                        // 8*MT, divisible by 8
    const int wg  = (blockIdx.x & 7) * (nwg >> 3) + (blockIdx.x >> 3);
    const int ntile = wg & 7, mtile = wg >> 3;
    const int bm = mtile * 128, bn = ntile * 128;

    const int tid  = threadIdx.x;
    const int wid  = tid >> 6;            // 0..3
    const int lane = tid & 63;
    const int wr = wid >> 1, wc = wid & 1;   // 2x2 wave quadrants (64x64)
    const int l15 = lane & 15, g = lane >> 4;

    f32x4 acc[4][4] = {};

    for (int k0 = 0; k0 < K; k0 += 64) {
        __syncthreads();                   // previous iter's reads done
        #pragma unroll
        for (int j = 0; j < 4; ++j) {
            const int c    = j * 256 + tid;       // 1024 chunks of 8 ushorts
            const int row  = c >> 3, wcn = c & 7;
            const int ldsi = row * 64 + (((wcn ^ (row & 7))) << 3);
            const int arow = bm + row;
            ulonglong2 avh = {0, 0}, avl = {0, 0};
            if (arow < M) {
                avh = *(const ulonglong2*)(Ah + (size_t)arow * K + k0 + wcn * 8);
                avl = *(const ulonglong2*)(Al + (size_t)arow * K + k0 + wcn * 8);
            }
            *(ulonglong2*)(lAh + ldsi) = avh;
            *(ulonglong2*)(lAl + ldsi) = avl;
            const size_t bo = (size_t)(bn + row) * K + k0 + wcn * 8;
            *(ulonglong2*)(lBh + ldsi) = *(const ulonglong2*)(Bh + bo);
            *(ulonglong2*)(lBl + ldsi) = *(const ulonglong2*)(Bl + bo);
        }
        __syncthreads();

        #pragma unroll
        for (int kk = 0; kk < 2; ++kk) {
            bf16x8 ah[4], al[4], bh[4], bl[4];
            #pragma unroll
            for (int m = 0; m < 4; ++m) {
                const int row = wr * 64 + m * 16 + l15;
                const int sc  = (kk * 4 + g) ^ (row & 7);
                const int idx = row * 64 + (sc << 3);
                ah[m] = *(const bf16x8*)(lAh + idx);
                al[m] = *(const bf16x8*)(lAl + idx);
            }
            #pragma unroll
            for (int n = 0; n < 4; ++n) {
                const int row = wc * 64 + n * 16 + l15;
                const int sc  = (kk * 4 + g) ^ (row & 7);
                const int idx = row * 64 + (sc << 3);
                bh[n] = *(const bf16x8*)(lBh + idx);
                bl[n] = *(const bf16x8*)(lBl + idx);
            }
            #pragma unroll
            for (int m = 0; m < 4; ++m)
                #pragma unroll
                for (int n = 0; n < 4; ++n) {
                    acc[m][n] = __builtin_amdgcn_mfma_f32_16x16x32_bf16(
                                    ah[m], bh[n], acc[m][n], 0, 0, 0);
                    acc[m][n] = __builtin_amdgcn_mfma_f32_16x16x32_bf16(
                                    ah[m], bl[n], acc[m][n], 0, 0, 0);
                    acc[m][n] = __builtin_amdgcn_mfma_f32_16x16x32_bf16(
                                    al[m], bh[n], acc[m][n], 0, 0, 0);
                }
        }
    }

    #pragma unroll
    for (int m = 0; m < 4; ++m) {
        #pragma unroll
        for (int i = 0; i < 4; ++i) {
            const int row = bm + wr * 64 + m * 16 + g * 4 + i;
            if (row >= M) continue;
            float* cp = C + (size_t)row * NC + bn + wc * 64 + l15;
            #pragma unroll
            for (int n = 0; n < 4; ++n)
                cp[n * 16] = acc[m][n][i];
        }
    }
}

// ---------------------------------------------------------------------------
// CSR build (per launch; edge list identical for both layers).
// ---------------------------------------------------------------------------
__global__ __launch_bounds__(256) void hist_deg(const int* __restrict__ dsts,
                                                int E, int ET, int* __restrict__ deg)
{
    const int w = blockIdx.x * blockDim.x + threadIdx.x;
    if (w >= ET) return;
    const int d = (w < E) ? dsts[w] : (w - E);   // w >= E: virtual self-loop
    atomicAdd(&deg[d], 1);
}

__global__ __launch_bounds__(256) void scan_rowptr(const int* __restrict__ deg,
                                                   int* __restrict__ rowptr,
                                                   int* __restrict__ cursor, int n)
{
    __shared__ int sums[256];
    const int tid   = threadIdx.x;
    const int chunk = (n + 255) / 256;
    const int lo = min(tid * chunk, n), hi = min(lo + chunk, n);

    int s = 0;
    for (int i = lo; i < hi; ++i) s += deg[i];
    sums[tid] = s;
    __syncthreads();

    for (int off = 1; off < 256; off <<= 1) {
        const int t = (tid >= off) ? sums[tid - off] : 0;
        __syncthreads();
        sums[tid] += t;
        __syncthreads();
    }

    int run = sums[tid] - s;   // exclusive prefix of this chunk
    for (int i = lo; i < hi; ++i) {
        rowptr[i] = run;
        cursor[i] = run;
        run += deg[i];
    }
    if (tid == 255) rowptr[n] = run;   // == ET
}

__global__ __launch_bounds__(256) void scatter_csr(const int* __restrict__ srcs,
                                                   const int* __restrict__ dsts,
                                                   int E, int ET,
                                                   int* __restrict__ cursor,
                                                   int* __restrict__ eidx)
{
    const int w = blockIdx.x * blockDim.x + threadIdx.x;
    if (w >= ET) return;
    int s, d;
    if (w < E) { s = srcs[w]; d = dsts[w]; }
    else       { s = w - E;   d = s; }
    const int pos = atomicAdd(&cursor[d], 1);
    eidx[pos] = s;
}

// ---------------------------------------------------------------------------
// Fused GATv2 edge pipeline + epilogue.
// TWO waves per dst node (one per head-half): wave (d, half) owns heads
// half*4..half*4+3 (1KB of each xl row). Halves per-edge serial work and
// doubles wave-level parallelism vs one-wave-per-node.
// Block = 256 threads = 4 waves = 2 nodes.
// MODE 0: h = elu(agg + bias); write bf16 hi/lo pair (feeds layer-2 GEMM)
// MODE 1: out[d*64+c] = mean_h(agg) + bias[c] (halves combined via LDS)
// ---------------------------------------------------------------------------
__device__ __forceinline__ float lrdot4(const float4 v, const float4 r, const float4 a)
{
    float t, s = 0.f;
    t = v.x + r.x; t = t > 0.f ? t : 0.2f * t; s = fmaf(t, a.x, s);
    t = v.y + r.y; t = t > 0.f ? t : 0.2f * t; s = fmaf(t, a.y, s);
    t = v.z + r.z; t = t > 0.f ? t : 0.2f * t; s = fmaf(t, a.z, s);
    t = v.w + r.w; t = t > 0.f ? t : 0.2f * t; s = fmaf(t, a.w, s);
    return s;
}

template<int MODE>
__global__ __launch_bounds__(256) void gat_fused(
    const float* __restrict__ xlr, const float* __restrict__ att,
    const float* __restrict__ bias, const int* __restrict__ rowptr,
    const int* __restrict__ eidx, int n, float* __restrict__ out,
    ushort* __restrict__ oh, ushort* __restrict__ ol)
{
    __shared__ float cmb[2][2][DD];        // [nodeLocal][half][channel], MODE 1

    const int tid  = threadIdx.x;
    const int wid  = tid >> 6;             // 0..3
    const int lane = tid & 63;
    const int nodeLocal = wid >> 1;        // 0..1
    const int half      = wid & 1;         // 0..1
    const int d = blockIdx.x * 2 + nodeLocal;
    const bool valid = (d < n);

    const int g16 = lane >> 4;                     // head within half (0..3)
    const int c4  = (lane & 15) << 2;              // 0..60
    const int o   = (half * 4 + g16) * 64 + c4;    // offset in [0,512)

    float4 r = make_float4(0.f, 0.f, 0.f, 0.f);
    if (valid)
        r = *reinterpret_cast<const float4*>(&xlr[(size_t)d * NC + 512 + o]);
    const float4 a = *reinterpret_cast<const float4*>(&att[o]);

    float4 acc = make_float4(0.f, 0.f, 0.f, 0.f);
    float  den = 0.f;

    int start = 0, end = 0;
    if (valid) { start = rowptr[d]; end = rowptr[d + 1]; }   // deg >= 1

    float4 v = make_float4(0.f, 0.f, 0.f, 0.f);
    if (start < end)
        v = *reinterpret_cast<const float4*>(&xlr[(size_t)eidx[start] * NC + o]);

    for (int e = start; e < end; ++e) {
        float4 nx = v;
        if (e + 1 < end)                                     // wave-uniform
            nx = *reinterpret_cast<const float4*>(&xlr[(size_t)eidx[e + 1] * NC + o]);

        float p = lrdot4(v, r, a);
        #pragma unroll
        for (int m = 1; m < 16; m <<= 1)        // reduce within 16-lane group
            p += __shfl_xor(p, m, 64);
        p = __expf(p);                          // logits O(1): no max shift
        den += p;

        acc.x = fmaf(v.x, p, acc.x); acc.y = fmaf(v.y, p, acc.y);
        acc.z = fmaf(v.z, p, acc.z); acc.w = fmaf(v.w, p, acc.w);

        v = nx;
    }

    const float inv = (end > start) ? 1.f / den : 0.f;

    if (MODE == 0) {
        if (valid) {
            const float4 bv = *reinterpret_cast<const float4*>(&bias[o]);
            float u[4];
            u[0] = fmaf(acc.x, inv, bv.x); u[1] = fmaf(acc.y, inv, bv.y);
            u[2] = fmaf(acc.z, inv, bv.z); u[3] = fmaf(acc.w, inv, bv.w);
            ushort hx[4], lx[4];
            #pragma unroll
            for (int j = 0; j < 4; ++j) {
                const float w = u[j] > 0.f ? u[j] : expm1f(u[j]);
                hx[j] = bf16_rne(w);
                lx[j] = bf16_rne(w - bf16_tof(hx[j]));
            }
            *reinterpret_cast<ushort4*>(&oh[(size_t)d * HD + o]) =
                make_ushort4(hx[0], hx[1], hx[2], hx[3]);
            *reinterpret_cast<ushort4*>(&ol[(size_t)d * HD + o]) =
                make_ushort4(lx[0], lx[1], lx[2], lx[3]);
        }
    } else {
        // sum this half's 4 heads: butterfly across g16 groups (lane bits 4,5)
        float4 t = make_float4(acc.x * inv, acc.y * inv, acc.z * inv, acc.w * inv);
        #pragma unroll
        for (int m = 16; m <= 32; m <<= 1) {
            t.x += __shfl_xor(t.x, m, 64);
            t.y += __shfl_xor(t.y, m, 64);
            t.z += __shfl_xor(t.z, m, 64);
            t.w += __shfl_xor(t.w, m, 64);
        }
        if (g16 == 0)
            *reinterpret_cast<float4*>(&cmb[nodeLocal][half][c4]) = t;
        __syncthreads();                       // all 4 waves reach this
        if (valid && half == 0 && g16 == 0) {
            const float4 s1 = *reinterpret_cast<const float4*>(&cmb[nodeLocal][1][c4]);
            const float4 bv = *reinterpret_cast<const float4*>(&bias[c4]);
            *reinterpret_cast<float4*>(&out[(size_t)d * DD + c4]) =
                make_float4(fmaf(t.x + s1.x, 0.125f, bv.x),
                            fmaf(t.y + s1.y, 0.125f, bv.y),
                            fmaf(t.z + s1.z, 0.125f, bv.z),
                            fmaf(t.w + s1.w, 0.125f, bv.w));
        }
    }
}

// ---------------------------------------------------------------------------
extern "C" void kernel_launch(void* const* d_in, const int* in_sizes, int n_in,
                              void* d_out, int out_size, void* d_ws, size_t ws_size,
                              hipStream_t stream)
{
    const float* x    = (const float*)d_in[0];
    const int*   ei   = (const int*)  d_in[1];
    const float* Wl1  = (const float*)d_in[2];
    const float* Wr1  = (const float*)d_in[3];
    const float* att1 = (const float*)d_in[4];
    const float* b1   = (const float*)d_in[5];
    const float* Wl2  = (const float*)d_in[6];
    const float* Wr2  = (const float*)d_in[7];
    const float* att2 = (const float*)d_in[8];
    const float* b2   = (const float*)d_in[9];

    const int N  = in_sizes[0] / DD;   // 20000
    const int E  = in_sizes[1] / 2;    // 320000
    const int ET = E + N;              // edges + self-loops

    const int* srcs = ei;
    const int* dsts = ei + E;

    // ---- workspace layout ----
    float*  xlr   = (float*)d_ws;                       // N*1024 f32 (82 MB)
    ushort* xs_h  = (ushort*)(xlr + (size_t)N * NC);    // N*64
    ushort* xs_l  = xs_h  + (size_t)N * DD;             // N*64
    ushort* h1_h  = xs_l  + (size_t)N * DD;             // N*512
    ushort* h1_l  = h1_h  + (size_t)N * HD;             // N*512
    ushort* bt1_h = h1_l  + (size_t)N * HD;             // 1024*64
    ushort* bt1_l = bt1_h + 1024 * DD;                  // 1024*64
    ushort* bt2_h = bt1_l + 1024 * DD;                  // 1024*512
    ushort* bt2_l = bt2_h + 1024 * HD;                  // 1024*512
    int* rowptr = (int*)(bt2_l + 1024 * HD);            // N+1
    int* deg    = rowptr + (N + 1);                     // N
    int* cursor = deg + N;                              // N
    int* eidx   = cursor + N;                           // ET

    const dim3 gblk(256);
    const int  eblk  = (ET + 255) / 256;
    const int  nblk2 = (N + 1) / 2;            // 2 nodes per block (2 waves each)
    const int  MT    = (N + 127) / 128;        // 157
    const int  gemm_grid = 8 * MT;             // 1256, divisible by 8

    // ---- CSR build (shared by both layers) ----
    hipMemsetAsync(deg, 0, (size_t)N * sizeof(int), stream);
    hist_deg   <<<eblk, gblk, 0, stream>>>(dsts, E, ET, deg);
    scan_rowptr<<<1,    gblk, 0, stream>>>(deg, rowptr, cursor, N);
    scatter_csr<<<eblk, gblk, 0, stream>>>(srcs, dsts, E, ET, cursor, eidx);

    // ---- split inputs / weights to bf16 hi/lo ----
    split_mat<<<(N * DD + 255) / 256, gblk, 0, stream>>>(x, xs_h, xs_l, N * DD);
    split_wT <<<(1024 * DD + 255) / 256, gblk, 0, stream>>>(Wl1, Wr1, bt1_h, bt1_l, 6);
    split_wT <<<(1024 * HD + 255) / 256, gblk, 0, stream>>>(Wl2, Wr2, bt2_h, bt2_l, 9);

    // ---- layer 1: GATv2Conv(64 -> 64, heads=8, concat) + ELU ----
    gemm_bf16x3<<<gemm_grid, gblk, 0, stream>>>(xs_h, xs_l, bt1_h, bt1_l, xlr, N, DD);
    gat_fused<0><<<nblk2, gblk, 0, stream>>>(xlr, att1, b1, rowptr, eidx, N,
                                             nullptr, h1_h, h1_l);

    // ---- layer 2: GATv2Conv(512 -> 64, heads=8, mean) ----
    gemm_bf16x3<<<gemm_grid, gblk, 0, stream>>>(h1_h, h1_l, bt2_h, bt2_l, xlr, N, HD);
    gat_fused<1><<<nblk2, gblk, 0, stream>>>(xlr, att2, b2, rowptr, eidx, N,
                                             (float*)d_out, nullptr, nullptr);
}

// Round 10
// 397.560 us; speedup vs baseline: 1.0381x; 1.0381x over previous
//
#include <hip/hip_runtime.h>
#include <hip/hip_fp16.h>
#include <math.h>

#define DD 64      // per-head channels
#define HH 8       // heads
#define HD 512     // HH*DD
#define NC 1024    // combined xl|xr row width

typedef __attribute__((ext_vector_type(8))) short bf16x8;
typedef __attribute__((ext_vector_type(4))) float f32x4;

// ---------------------------------------------------------------------------
// bf16 split helpers (round-to-nearest-even)
// ---------------------------------------------------------------------------
__device__ __forceinline__ ushort bf16_rne(float f) {
    uint u = __float_as_uint(f);
    u += 0x7fffu + ((u >> 16) & 1u);
    return (ushort)(u >> 16);
}
__device__ __forceinline__ float bf16_tof(ushort h) {
    return __uint_as_float(((uint)h) << 16);
}

// 4 consecutive fp16 -> float4 (single 8B load)
__device__ __forceinline__ float4 load_h4(const __half* p) {
    uint2 raw = *reinterpret_cast<const uint2*>(p);
    const __half2 a = *reinterpret_cast<const __half2*>(&raw.x);
    const __half2 b = *reinterpret_cast<const __half2*>(&raw.y);
    const float2 fa = __half22float2(a), fb = __half22float2(b);
    return make_float4(fa.x, fa.y, fb.x, fb.y);
}

// elementwise fp32 -> (hi, lo) bf16 pair
__global__ __launch_bounds__(256) void split_mat(const float* __restrict__ in,
                                                 ushort* __restrict__ hi,
                                                 ushort* __restrict__ lo, int total)
{
    const int i = blockIdx.x * 256 + threadIdx.x;
    if (i >= total) return;
    const float f = in[i];
    const ushort h = bf16_rne(f);
    hi[i] = h;
    lo[i] = bf16_rne(f - bf16_tof(h));
}

// W0,W1: [K][512] fp32 -> Bt: [1024][K] bf16 hi/lo (transposed, concatenated)
__global__ __launch_bounds__(256) void split_wT(const float* __restrict__ W0,
                                                const float* __restrict__ W1,
                                                ushort* __restrict__ hi,
                                                ushort* __restrict__ lo, int kshift)
{
    const int K = 1 << kshift;
    const int i = blockIdx.x * 256 + threadIdx.x;    // i = c*K + k
    if (i >= 1024 * K) return;
    const int c = i >> kshift, k = i & (K - 1);
    const float* W = (c < 512) ? W0 : W1;
    const float f = W[(size_t)k * 512 + (c & 511)];
    const ushort h = bf16_rne(f);
    hi[i] = h;
    lo[i] = bf16_rne(f - bf16_tof(h));
}

// ---------------------------------------------------------------------------
// bf16x3 split-precision MFMA GEMM; C written as fp16 (feeds the gather).
// ---------------------------------------------------------------------------
__global__ __launch_bounds__(256) void gemm_bf16x3(
    const ushort* __restrict__ Ah, const ushort* __restrict__ Al,
    const ushort* __restrict__ Bh, const ushort* __restrict__ Bl,
    __half* __restrict__ C, int M, int K)
{
    __shared__ __align__(16) ushort lAh[128 * 64];
    __shared__ __align__(16) ushort lAl[128 * 64];
    __shared__ __align__(16) ushort lBh[128 * 64];
    __shared__ __align__(16) ushort lBl[128 * 64];

    const int nwg = gridDim.x;                        // 8*MT, divisible by 8
    const int wg  = (blockIdx.x & 7) * (nwg >> 3) + (blockIdx.x >> 3);
    const int ntile = wg & 7, mtile = wg >> 3;
    const int bm = mtile * 128, bn = ntile * 128;

    const int tid  = threadIdx.x;
    const int wid  = tid >> 6;            // 0..3
    const int lane = tid & 63;
    const int wr = wid >> 1, wc = wid & 1;   // 2x2 wave quadrants (64x64)
    const int l15 = lane & 15, g = lane >> 4;

    f32x4 acc[4][4] = {};

    for (int k0 = 0; k0 < K; k0 += 64) {
        __syncthreads();                   // previous iter's reads done
        #pragma unroll
        for (int j = 0; j < 4; ++j) {
            const int c    = j * 256 + tid;       // 1024 chunks of 8 ushorts
            const int row  = c >> 3, wcn = c & 7;
            const int ldsi = row * 64 + (((wcn ^ (row & 7))) << 3);
            const int arow = bm + row;
            ulonglong2 avh = {0, 0}, avl = {0, 0};
            if (arow < M) {
                avh = *(const ulonglong2*)(Ah + (size_t)arow * K + k0 + wcn * 8);
                avl = *(const ulonglong2*)(Al + (size_t)arow * K + k0 + wcn * 8);
            }
            *(ulonglong2*)(lAh + ldsi) = avh;
            *(ulonglong2*)(lAl + ldsi) = avl;
            const size_t bo = (size_t)(bn + row) * K + k0 + wcn * 8;
            *(ulonglong2*)(lBh + ldsi) = *(const ulonglong2*)(Bh + bo);
            *(ulonglong2*)(lBl + ldsi) = *(const ulonglong2*)(Bl + bo);
        }
        __syncthreads();

        #pragma unroll
        for (int kk = 0; kk < 2; ++kk) {
            bf16x8 ah[4], al[4], bh[4], bl[4];
            #pragma unroll
            for (int m = 0; m < 4; ++m) {
                const int row = wr * 64 + m * 16 + l15;
                const int sc  = (kk * 4 + g) ^ (row & 7);
                const int idx = row * 64 + (sc << 3);
                ah[m] = *(const bf16x8*)(lAh + idx);
                al[m] = *(const bf16x8*)(lAl + idx);
            }
            #pragma unroll
            for (int n = 0; n < 4; ++n) {
                const int row = wc * 64 + n * 16 + l15;
                const int sc  = (kk * 4 + g) ^ (row & 7);
                const int idx = row * 64 + (sc << 3);
                bh[n] = *(const bf16x8*)(lBh + idx);
                bl[n] = *(const bf16x8*)(lBl + idx);
            }
            #pragma unroll
            for (int m = 0; m < 4; ++m)
                #pragma unroll
                for (int n = 0; n < 4; ++n) {
                    acc[m][n] = __builtin_amdgcn_mfma_f32_16x16x32_bf16(
                                    ah[m], bh[n], acc[m][n], 0, 0, 0);
                    acc[m][n] = __builtin_amdgcn_mfma_f32_16x16x32_bf16(
                                    ah[m], bl[n], acc[m][n], 0, 0, 0);
                    acc[m][n] = __builtin_amdgcn_mfma_f32_16x16x32_bf16(
                                    al[m], bh[n], acc[m][n], 0, 0, 0);
                }
        }
    }

    #pragma unroll
    for (int m = 0; m < 4; ++m) {
        #pragma unroll
        for (int i = 0; i < 4; ++i) {
            const int row = bm + wr * 64 + m * 16 + g * 4 + i;
            if (row >= M) continue;
            __half* cp = C + (size_t)row * NC + bn + wc * 64 + l15;
            #pragma unroll
            for (int n = 0; n < 4; ++n)
                cp[n * 16] = __float2half_rn(acc[m][n][i]);
        }
    }
}

// ---------------------------------------------------------------------------
// CSR build (per launch; edge list identical for both layers).
// ---------------------------------------------------------------------------
__global__ __launch_bounds__(256) void hist_deg(const int* __restrict__ dsts,
                                                int E, int ET, int* __restrict__ deg)
{
    const int w = blockIdx.x * blockDim.x + threadIdx.x;
    if (w >= ET) return;
    const int d = (w < E) ? dsts[w] : (w - E);   // w >= E: virtual self-loop
    atomicAdd(&deg[d], 1);
}

__global__ __launch_bounds__(256) void scan_rowptr(const int* __restrict__ deg,
                                                   int* __restrict__ rowptr,
                                                   int* __restrict__ cursor, int n)
{
    __shared__ int sums[256];
    const int tid   = threadIdx.x;
    const int chunk = (n + 255) / 256;
    const int lo = min(tid * chunk, n), hi = min(lo + chunk, n);

    int s = 0;
    for (int i = lo; i < hi; ++i) s += deg[i];
    sums[tid] = s;
    __syncthreads();

    for (int off = 1; off < 256; off <<= 1) {
        const int t = (tid >= off) ? sums[tid - off] : 0;
        __syncthreads();
        sums[tid] += t;
        __syncthreads();
    }

    int run = sums[tid] - s;   // exclusive prefix of this chunk
    for (int i = lo; i < hi; ++i) {
        rowptr[i] = run;
        cursor[i] = run;
        run += deg[i];
    }
    if (tid == 255) rowptr[n] = run;   // == ET
}

__global__ __launch_bounds__(256) void scatter_csr(const int* __restrict__ srcs,
                                                   const int* __restrict__ dsts,
                                                   int E, int ET,
                                                   int* __restrict__ cursor,
                                                   int* __restrict__ eidx)
{
    const int w = blockIdx.x * blockDim.x + threadIdx.x;
    if (w >= ET) return;
    int s, d;
    if (w < E) { s = srcs[w]; d = dsts[w]; }
    else       { s = w - E;   d = s; }
    const int pos = atomicAdd(&cursor[d], 1);
    eidx[pos] = s;
}

// ---------------------------------------------------------------------------
// Fused GATv2 edge pipeline + epilogue. Two waves per dst node (one per
// head-half); xlr rows stored fp16 (halves gather bytes vs fp32).
// Block = 256 threads = 4 waves = 2 nodes.
// MODE 0: h = elu(agg + bias); write bf16 hi/lo pair (feeds layer-2 GEMM)
// MODE 1: out[d*64+c] = mean_h(agg) + bias[c] (halves combined via LDS)
// ---------------------------------------------------------------------------
__device__ __forceinline__ float lrdot4(const float4 v, const float4 r, const float4 a)
{
    float t, s = 0.f;
    t = v.x + r.x; t = t > 0.f ? t : 0.2f * t; s = fmaf(t, a.x, s);
    t = v.y + r.y; t = t > 0.f ? t : 0.2f * t; s = fmaf(t, a.y, s);
    t = v.z + r.z; t = t > 0.f ? t : 0.2f * t; s = fmaf(t, a.z, s);
    t = v.w + r.w; t = t > 0.f ? t : 0.2f * t; s = fmaf(t, a.w, s);
    return s;
}

template<int MODE>
__global__ __launch_bounds__(256) void gat_fused(
    const __half* __restrict__ xlr, const float* __restrict__ att,
    const float* __restrict__ bias, const int* __restrict__ rowptr,
    const int* __restrict__ eidx, int n, float* __restrict__ out,
    ushort* __restrict__ oh, ushort* __restrict__ ol)
{
    __shared__ float cmb[2][2][DD];        // [nodeLocal][half][channel], MODE 1

    const int tid  = threadIdx.x;
    const int wid  = tid >> 6;             // 0..3
    const int lane = tid & 63;
    const int nodeLocal = wid >> 1;        // 0..1
    const int half      = wid & 1;         // 0..1
    const int d = blockIdx.x * 2 + nodeLocal;
    const bool valid = (d < n);

    const int g16 = lane >> 4;                     // head within half (0..3)
    const int c4  = (lane & 15) << 2;              // 0..60
    const int o   = (half * 4 + g16) * 64 + c4;    // offset in [0,512)

    float4 r = make_float4(0.f, 0.f, 0.f, 0.f);
    if (valid)
        r = load_h4(&xlr[(size_t)d * NC + 512 + o]);
    const float4 a = *reinterpret_cast<const float4*>(&att[o]);

    float4 acc = make_float4(0.f, 0.f, 0.f, 0.f);
    float  den = 0.f;

    int start = 0, end = 0;
    if (valid) { start = rowptr[d]; end = rowptr[d + 1]; }   // deg >= 1

    float4 v = make_float4(0.f, 0.f, 0.f, 0.f);
    if (start < end)
        v = load_h4(&xlr[(size_t)eidx[start] * NC + o]);

    for (int e = start; e < end; ++e) {
        float4 nx = v;
        if (e + 1 < end)                                     // wave-uniform
            nx = load_h4(&xlr[(size_t)eidx[e + 1] * NC + o]);

        float p = lrdot4(v, r, a);
        #pragma unroll
        for (int m = 1; m < 16; m <<= 1)        // reduce within 16-lane group
            p += __shfl_xor(p, m, 64);
        p = __expf(p);                          // logits O(1): no max shift
        den += p;

        acc.x = fmaf(v.x, p, acc.x); acc.y = fmaf(v.y, p, acc.y);
        acc.z = fmaf(v.z, p, acc.z); acc.w = fmaf(v.w, p, acc.w);

        v = nx;
    }

    const float inv = (end > start) ? 1.f / den : 0.f;

    if (MODE == 0) {
        if (valid) {
            const float4 bv = *reinterpret_cast<const float4*>(&bias[o]);
            float u[4];
            u[0] = fmaf(acc.x, inv, bv.x); u[1] = fmaf(acc.y, inv, bv.y);
            u[2] = fmaf(acc.z, inv, bv.z); u[3] = fmaf(acc.w, inv, bv.w);
            ushort hx[4], lx[4];
            #pragma unroll
            for (int j = 0; j < 4; ++j) {
                const float w = u[j] > 0.f ? u[j] : expm1f(u[j]);
                hx[j] = bf16_rne(w);
                lx[j] = bf16_rne(w - bf16_tof(hx[j]));
            }
            *reinterpret_cast<ushort4*>(&oh[(size_t)d * HD + o]) =
                make_ushort4(hx[0], hx[1], hx[2], hx[3]);
            *reinterpret_cast<ushort4*>(&ol[(size_t)d * HD + o]) =
                make_ushort4(lx[0], lx[1], lx[2], lx[3]);
        }
    } else {
        // sum this half's 4 heads: butterfly across g16 groups (lane bits 4,5)
        float4 t = make_float4(acc.x * inv, acc.y * inv, acc.z * inv, acc.w * inv);
        #pragma unroll
        for (int m = 16; m <= 32; m <<= 1) {
            t.x += __shfl_xor(t.x, m, 64);
            t.y += __shfl_xor(t.y, m, 64);
            t.z += __shfl_xor(t.z, m, 64);
            t.w += __shfl_xor(t.w, m, 64);
        }
        if (g16 == 0)
            *reinterpret_cast<float4*>(&cmb[nodeLocal][half][c4]) = t;
        __syncthreads();                       // all 4 waves reach this
        if (valid && half == 0 && g16 == 0) {
            const float4 s1 = *reinterpret_cast<const float4*>(&cmb[nodeLocal][1][c4]);
            const float4 bv = *reinterpret_cast<const float4*>(&bias[c4]);
            *reinterpret_cast<float4*>(&out[(size_t)d * DD + c4]) =
                make_float4(fmaf(t.x + s1.x, 0.125f, bv.x),
                            fmaf(t.y + s1.y, 0.125f, bv.y),
                            fmaf(t.z + s1.z, 0.125f, bv.z),
                            fmaf(t.w + s1.w, 0.125f, bv.w));
        }
    }
}

// ---------------------------------------------------------------------------
extern "C" void kernel_launch(void* const* d_in, const int* in_sizes, int n_in,
                              void* d_out, int out_size, void* d_ws, size_t ws_size,
                              hipStream_t stream)
{
    const float* x    = (const float*)d_in[0];
    const int*   ei   = (const int*)  d_in[1];
    const float* Wl1  = (const float*)d_in[2];
    const float* Wr1  = (const float*)d_in[3];
    const float* att1 = (const float*)d_in[4];
    const float* b1   = (const float*)d_in[5];
    const float* Wl2  = (const float*)d_in[6];
    const float* Wr2  = (const float*)d_in[7];
    const float* att2 = (const float*)d_in[8];
    const float* b2   = (const float*)d_in[9];

    const int N  = in_sizes[0] / DD;   // 20000
    const int E  = in_sizes[1] / 2;    // 320000
    const int ET = E + N;              // edges + self-loops

    const int* srcs = ei;
    const int* dsts = ei + E;

    // ---- workspace layout ----
    __half* xlr   = (__half*)d_ws;                      // N*1024 f16 (41 MB)
    ushort* xs_h  = (ushort*)(xlr + (size_t)N * NC);    // N*64
    ushort* xs_l  = xs_h  + (size_t)N * DD;             // N*64
    ushort* h1_h  = xs_l  + (size_t)N * DD;             // N*512
    ushort* h1_l  = h1_h  + (size_t)N * HD;             // N*512
    ushort* bt1_h = h1_l  + (size_t)N * HD;             // 1024*64
    ushort* bt1_l = bt1_h + 1024 * DD;                  // 1024*64
    ushort* bt2_h = bt1_l + 1024 * DD;                  // 1024*512
    ushort* bt2_l = bt2_h + 1024 * HD;                  // 1024*512
    int* rowptr = (int*)(bt2_l + 1024 * HD);            // N+1
    int* deg    = rowptr + (N + 1);                     // N
    int* cursor = deg + N;                              // N
    int* eidx   = cursor + N;                           // ET

    const dim3 gblk(256);
    const int  eblk  = (ET + 255) / 256;
    const int  nblk2 = (N + 1) / 2;            // 2 nodes per block (2 waves each)
    const int  MT    = (N + 127) / 128;        // 157
    const int  gemm_grid = 8 * MT;             // 1256, divisible by 8

    // ---- CSR build (shared by both layers) ----
    hipMemsetAsync(deg, 0, (size_t)N * sizeof(int), stream);
    hist_deg   <<<eblk, gblk, 0, stream>>>(dsts, E, ET, deg);
    scan_rowptr<<<1,    gblk, 0, stream>>>(deg, rowptr, cursor, N);
    scatter_csr<<<eblk, gblk, 0, stream>>>(srcs, dsts, E, ET, cursor, eidx);

    // ---- split inputs / weights to bf16 hi/lo ----
    split_mat<<<(N * DD + 255) / 256, gblk, 0, stream>>>(x, xs_h, xs_l, N * DD);
    split_wT <<<(1024 * DD + 255) / 256, gblk, 0, stream>>>(Wl1, Wr1, bt1_h, bt1_l, 6);
    split_wT <<<(1024 * HD + 255) / 256, gblk, 0, stream>>>(Wl2, Wr2, bt2_h, bt2_l, 9);

    // ---- layer 1: GATv2Conv(64 -> 64, heads=8, concat) + ELU ----
    gemm_bf16x3<<<gemm_grid, gblk, 0, stream>>>(xs_h, xs_l, bt1_h, bt1_l, xlr, N, DD);
    gat_fused<0><<<nblk2, gblk, 0, stream>>>(xlr, att1, b1, rowptr, eidx, N,
                                             nullptr, h1_h, h1_l);

    // ---- layer 2: GATv2Conv(512 -> 64, heads=8, mean) ----
    gemm_bf16x3<<<gemm_grid, gblk, 0, stream>>>(h1_h, h1_l, bt2_h, bt2_l, xlr, N, HD);
    gat_fused<1><<<nblk2, gblk, 0, stream>>>(xlr, att2, b2, rowptr, eidx, N,
                                             (float*)d_out, nullptr, nullptr);
}

// Round 11
// 307.312 us; speedup vs baseline: 1.3430x; 1.2937x over previous
//
#include <hip/hip_runtime.h>
#include <hip/hip_fp16.h>
#include <math.h>

#define DD 64      // per-head channels
#define HH 8       // heads
#define HD 512     // HH*DD
#define NC 1024    // combined xl|xr row width

typedef __attribute__((ext_vector_type(8))) short bf16x8;
typedef __attribute__((ext_vector_type(4))) float f32x4;
typedef __attribute__((ext_vector_type(8))) unsigned short ushort8;

// ---------------------------------------------------------------------------
// bf16 split helpers (round-to-nearest-even)
// ---------------------------------------------------------------------------
__device__ __forceinline__ ushort bf16_rne(float f) {
    uint u = __float_as_uint(f);
    u += 0x7fffu + ((u >> 16) & 1u);
    return (ushort)(u >> 16);
}
__device__ __forceinline__ float bf16_tof(ushort h) {
    return __uint_as_float(((uint)h) << 16);
}
__device__ __forceinline__ float h2f(ushort u) {
    __half h; *reinterpret_cast<ushort*>(&h) = u; return __half2float(h);
}

// elementwise fp32 -> (hi, lo) bf16 pair
__global__ __launch_bounds__(256) void split_mat(const float* __restrict__ in,
                                                 ushort* __restrict__ hi,
                                                 ushort* __restrict__ lo, int total)
{
    const int i = blockIdx.x * 256 + threadIdx.x;
    if (i >= total) return;
    const float f = in[i];
    const ushort h = bf16_rne(f);
    hi[i] = h;
    lo[i] = bf16_rne(f - bf16_tof(h));
}

// W0,W1: [K][512] fp32 -> Bt: [1024][K] bf16 hi/lo (transposed, concatenated)
__global__ __launch_bounds__(256) void split_wT(const float* __restrict__ W0,
                                                const float* __restrict__ W1,
                                                ushort* __restrict__ hi,
                                                ushort* __restrict__ lo, int kshift)
{
    const int K = 1 << kshift;
    const int i = blockIdx.x * 256 + threadIdx.x;    // i = c*K + k
    if (i >= 1024 * K) return;
    const int c = i >> kshift, k = i & (K - 1);
    const float* W = (c < 512) ? W0 : W1;
    const float f = W[(size_t)k * 512 + (c & 511)];
    const ushort h = bf16_rne(f);
    hi[i] = h;
    lo[i] = bf16_rne(f - bf16_tof(h));
}

// ---------------------------------------------------------------------------
// bf16x3 split-precision MFMA GEMM; C written as fp16 (feeds the gather).
// ---------------------------------------------------------------------------
__global__ __launch_bounds__(256) void gemm_bf16x3(
    const ushort* __restrict__ Ah, const ushort* __restrict__ Al,
    const ushort* __restrict__ Bh, const ushort* __restrict__ Bl,
    __half* __restrict__ C, int M, int K)
{
    __shared__ __align__(16) ushort lAh[128 * 64];
    __shared__ __align__(16) ushort lAl[128 * 64];
    __shared__ __align__(16) ushort lBh[128 * 64];
    __shared__ __align__(16) ushort lBl[128 * 64];

    const int nwg = gridDim.x;                        // 8*MT, divisible by 8
    const int wg  = (blockIdx.x & 7) * (nwg >> 3) + (blockIdx.x >> 3);
    const int ntile = wg & 7, mtile = wg >> 3;
    const int bm = mtile * 128, bn = ntile * 128;

    const int tid  = threadIdx.x;
    const int wid  = tid >> 6;            // 0..3
    const int lane = tid & 63;
    const int wr = wid >> 1, wc = wid & 1;   // 2x2 wave quadrants (64x64)
    const int l15 = lane & 15, g = lane >> 4;

    f32x4 acc[4][4] = {};

    for (int k0 = 0; k0 < K; k0 += 64) {
        __syncthreads();                   // previous iter's reads done
        #pragma unroll
        for (int j = 0; j < 4; ++j) {
            const int c    = j * 256 + tid;       // 1024 chunks of 8 ushorts
            const int row  = c >> 3, wcn = c & 7;
            const int ldsi = row * 64 + (((wcn ^ (row & 7))) << 3);
            const int arow = bm + row;
            ulonglong2 avh = {0, 0}, avl = {0, 0};
            if (arow < M) {
                avh = *(const ulonglong2*)(Ah + (size_t)arow * K + k0 + wcn * 8);
                avl = *(const ulonglong2*)(Al + (size_t)arow * K + k0 + wcn * 8);
            }
            *(ulonglong2*)(lAh + ldsi) = avh;
            *(ulonglong2*)(lAl + ldsi) = avl;
            const size_t bo = (size_t)(bn + row) * K + k0 + wcn * 8;
            *(ulonglong2*)(lBh + ldsi) = *(const ulonglong2*)(Bh + bo);
            *(ulonglong2*)(lBl + ldsi) = *(const ulonglong2*)(Bl + bo);
        }
        __syncthreads();

        #pragma unroll
        for (int kk = 0; kk < 2; ++kk) {
            bf16x8 ah[4], al[4], bh[4], bl[4];
            #pragma unroll
            for (int m = 0; m < 4; ++m) {
                const int row = wr * 64 + m * 16 + l15;
                const int sc  = (kk * 4 + g) ^ (row & 7);
                const int idx = row * 64 + (sc << 3);
                ah[m] = *(const bf16x8*)(lAh + idx);
                al[m] = *(const bf16x8*)(lAl + idx);
            }
            #pragma unroll
            for (int n = 0; n < 4; ++n) {
                const int row = wc * 64 + n * 16 + l15;
                const int sc  = (kk * 4 + g) ^ (row & 7);
                const int idx = row * 64 + (sc << 3);
                bh[n] = *(const bf16x8*)(lBh + idx);
                bl[n] = *(const bf16x8*)(lBl + idx);
            }
            #pragma unroll
            for (int m = 0; m < 4; ++m)
                #pragma unroll
                for (int n = 0; n < 4; ++n) {
                    acc[m][n] = __builtin_amdgcn_mfma_f32_16x16x32_bf16(
                                    ah[m], bh[n], acc[m][n], 0, 0, 0);
                    acc[m][n] = __builtin_amdgcn_mfma_f32_16x16x32_bf16(
                                    ah[m], bl[n], acc[m][n], 0, 0, 0);
                    acc[m][n] = __builtin_amdgcn_mfma_f32_16x16x32_bf16(
                                    al[m], bh[n], acc[m][n], 0, 0, 0);
                }
        }
    }

    #pragma unroll
    for (int m = 0; m < 4; ++m) {
        #pragma unroll
        for (int i = 0; i < 4; ++i) {
            const int row = bm + wr * 64 + m * 16 + g * 4 + i;
            if (row >= M) continue;
            __half* cp = C + (size_t)row * NC + bn + wc * 64 + l15;
            #pragma unroll
            for (int n = 0; n < 4; ++n)
                cp[n * 16] = __float2half_rn(acc[m][n][i]);
        }
    }
}

// ---------------------------------------------------------------------------
// CSR build (per launch; edge list identical for both layers).
// ---------------------------------------------------------------------------
__global__ __launch_bounds__(256) void hist_deg(const int* __restrict__ dsts,
                                                int E, int ET, int* __restrict__ deg)
{
    const int w = blockIdx.x * blockDim.x + threadIdx.x;
    if (w >= ET) return;
    const int d = (w < E) ? dsts[w] : (w - E);   // w >= E: virtual self-loop
    atomicAdd(&deg[d], 1);
}

__global__ __launch_bounds__(256) void scan_rowptr(const int* __restrict__ deg,
                                                   int* __restrict__ rowptr,
                                                   int* __restrict__ cursor, int n)
{
    __shared__ int sums[256];
    const int tid   = threadIdx.x;
    const int chunk = (n + 255) / 256;
    const int lo = min(tid * chunk, n), hi = min(lo + chunk, n);

    int s = 0;
    for (int i = lo; i < hi; ++i) s += deg[i];
    sums[tid] = s;
    __syncthreads();

    for (int off = 1; off < 256; off <<= 1) {
        const int t = (tid >= off) ? sums[tid - off] : 0;
        __syncthreads();
        sums[tid] += t;
        __syncthreads();
    }

    int run = sums[tid] - s;   // exclusive prefix of this chunk
    for (int i = lo; i < hi; ++i) {
        rowptr[i] = run;
        cursor[i] = run;
        run += deg[i];
    }
    if (tid == 255) rowptr[n] = run;   // == ET
}

__global__ __launch_bounds__(256) void scatter_csr(const int* __restrict__ srcs,
                                                   const int* __restrict__ dsts,
                                                   int E, int ET,
                                                   int* __restrict__ cursor,
                                                   int* __restrict__ eidx)
{
    const int w = blockIdx.x * blockDim.x + threadIdx.x;
    if (w >= ET) return;
    int s, d;
    if (w < E) { s = srcs[w]; d = dsts[w]; }
    else       { s = w - E;   d = s; }
    const int pos = atomicAdd(&cursor[d], 1);
    eidx[pos] = s;
}

// ---------------------------------------------------------------------------
// Fused GATv2 edge pipeline + epilogue.
// ONE wave per dst node; lane owns 8 contiguous channels (head = lane>>3).
// Per edge: one 16B/lane load (full 1KB fp16 row), fp32 compute, 3-step
// shfl_xor logit reduce (masks 1,2,4). 2-edge unrolled, branch-free
// clamped prefetch. Block = 256 threads = 4 waves = 4 nodes.
// MODE 0: h = elu(agg + bias); write bf16 hi/lo pair (feeds layer-2 GEMM)
// MODE 1: out[d*64+c] = mean_h(agg) + bias[c] (in-wave shuffle mean)
// ---------------------------------------------------------------------------
__device__ __forceinline__ void edge_step(const ushort8 v,
                                          const float* __restrict__ r,
                                          const float* __restrict__ a,
                                          float* __restrict__ acc, float& den)
{
    float vf[8], s = 0.f;
    #pragma unroll
    for (int j = 0; j < 8; ++j) {
        vf[j] = h2f(v[j]);
        float t = vf[j] + r[j];
        t = t > 0.f ? t : 0.2f * t;          // leaky_relu(0.2)
        s = fmaf(t, a[j], s);
    }
    s += __shfl_xor(s, 1, 64);               // reduce within 8-lane head group
    s += __shfl_xor(s, 2, 64);
    s += __shfl_xor(s, 4, 64);
    const float p = __expf(s);               // logits O(1): no max shift
    den += p;
    #pragma unroll
    for (int j = 0; j < 8; ++j) acc[j] = fmaf(p, vf[j], acc[j]);
}

template<int MODE>
__global__ __launch_bounds__(256) void gat_fused(
    const __half* __restrict__ xlr, const float* __restrict__ att,
    const float* __restrict__ bias, const int* __restrict__ rowptr,
    const int* __restrict__ eidx, int n, float* __restrict__ out,
    ushort* __restrict__ oh, ushort* __restrict__ ol)
{
    const int d    = (blockIdx.x * blockDim.x + threadIdx.x) >> 6;
    const int lane = threadIdx.x & 63;
    if (d >= n) return;

    const int o = lane * 8;                  // channels [o, o+8)

    // xr row (fp16) and att (fp32) -> registers
    float r[8], a[8];
    {
        const ushort8 rv = *(const ushort8*)((const ushort*)xlr + (size_t)d * NC + 512 + o);
        #pragma unroll
        for (int j = 0; j < 8; ++j) r[j] = h2f(rv[j]);
        *(float4*)&a[0] = *(const float4*)(att + o);
        *(float4*)&a[4] = *(const float4*)(att + o + 4);
    }

    float acc[8] = {};
    float den = 0.f;

    const int start = rowptr[d];
    const int end   = rowptr[d + 1];         // deg >= 1 (self-loop)
    const int last  = end - 1;
    const ushort* xb = (const ushort*)xlr;

    ushort8 v0 = *(const ushort8*)(xb + ((size_t)eidx[start] << 10) + o);
    ushort8 v1 = *(const ushort8*)(xb + ((size_t)eidx[min(start + 1, last)] << 10) + o);

    int e = start;
    for (; e + 1 < end; e += 2) {
        const int i2 = min(e + 2, last), i3 = min(e + 3, last);
        const ushort8 n0 = *(const ushort8*)(xb + ((size_t)eidx[i2] << 10) + o);
        const ushort8 n1 = *(const ushort8*)(xb + ((size_t)eidx[i3] << 10) + o);
        edge_step(v0, r, a, acc, den);
        edge_step(v1, r, a, acc, den);
        v0 = n0; v1 = n1;
    }
    if (e < end) edge_step(v0, r, a, acc, den);

    const float inv = 1.f / den;

    if (MODE == 0) {
        // elu(agg + b1), emitted as bf16 hi/lo split for the next GEMM
        float bv[8];
        *(float4*)&bv[0] = *(const float4*)(bias + o);
        *(float4*)&bv[4] = *(const float4*)(bias + o + 4);
        ushort8 hx, lx;
        #pragma unroll
        for (int j = 0; j < 8; ++j) {
            const float u = fmaf(acc[j], inv, bv[j]);
            const float w = u > 0.f ? u : expm1f(u);
            const ushort h = bf16_rne(w);
            hx[j] = h;
            lx[j] = bf16_rne(w - bf16_tof(h));
        }
        *(ushort8*)(oh + (size_t)d * HD + o) = hx;
        *(ushort8*)(ol + (size_t)d * HD + o) = lx;
    } else {
        // mean over 8 heads: reduce across lane bits 3,4,5
        float m[8];
        #pragma unroll
        for (int j = 0; j < 8; ++j) m[j] = acc[j] * inv;
        #pragma unroll
        for (int j = 0; j < 8; ++j) {
            m[j] += __shfl_xor(m[j], 8,  64);
            m[j] += __shfl_xor(m[j], 16, 64);
            m[j] += __shfl_xor(m[j], 32, 64);
        }
        if (lane < 8) {                      // lane covers channels lane*8..+7
            const int c = lane * 8;
            float4 r0, r1;
            r0.x = fmaf(m[0], 0.125f, bias[c + 0]);
            r0.y = fmaf(m[1], 0.125f, bias[c + 1]);
            r0.z = fmaf(m[2], 0.125f, bias[c + 2]);
            r0.w = fmaf(m[3], 0.125f, bias[c + 3]);
            r1.x = fmaf(m[4], 0.125f, bias[c + 4]);
            r1.y = fmaf(m[5], 0.125f, bias[c + 5]);
            r1.z = fmaf(m[6], 0.125f, bias[c + 6]);
            r1.w = fmaf(m[7], 0.125f, bias[c + 7]);
            *(float4*)(out + (size_t)d * DD + c)     = r0;
            *(float4*)(out + (size_t)d * DD + c + 4) = r1;
        }
    }
}

// ---------------------------------------------------------------------------
extern "C" void kernel_launch(void* const* d_in, const int* in_sizes, int n_in,
                              void* d_out, int out_size, void* d_ws, size_t ws_size,
                              hipStream_t stream)
{
    const float* x    = (const float*)d_in[0];
    const int*   ei   = (const int*)  d_in[1];
    const float* Wl1  = (const float*)d_in[2];
    const float* Wr1  = (const float*)d_in[3];
    const float* att1 = (const float*)d_in[4];
    const float* b1   = (const float*)d_in[5];
    const float* Wl2  = (const float*)d_in[6];
    const float* Wr2  = (const float*)d_in[7];
    const float* att2 = (const float*)d_in[8];
    const float* b2   = (const float*)d_in[9];

    const int N  = in_sizes[0] / DD;   // 20000
    const int E  = in_sizes[1] / 2;    // 320000
    const int ET = E + N;              // edges + self-loops

    const int* srcs = ei;
    const int* dsts = ei + E;

    // ---- workspace layout ----
    __half* xlr   = (__half*)d_ws;                      // N*1024 f16 (41 MB)
    ushort* xs_h  = (ushort*)(xlr + (size_t)N * NC);    // N*64
    ushort* xs_l  = xs_h  + (size_t)N * DD;             // N*64
    ushort* h1_h  = xs_l  + (size_t)N * DD;             // N*512
    ushort* h1_l  = h1_h  + (size_t)N * HD;             // N*512
    ushort* bt1_h = h1_l  + (size_t)N * HD;             // 1024*64
    ushort* bt1_l = bt1_h + 1024 * DD;                  // 1024*64
    ushort* bt2_h = bt1_l + 1024 * DD;                  // 1024*512
    ushort* bt2_l = bt2_h + 1024 * HD;                  // 1024*512
    int* rowptr = (int*)(bt2_l + 1024 * HD);            // N+1
    int* deg    = rowptr + (N + 1);                     // N
    int* cursor = deg + N;                              // N
    int* eidx   = cursor + N;                           // ET

    const dim3 gblk(256);
    const int  eblk  = (ET + 255) / 256;
    const int  nblk  = (N + 3) / 4;            // one WAVE per node, 4 nodes/block
    const int  MT    = (N + 127) / 128;        // 157
    const int  gemm_grid = 8 * MT;             // 1256, divisible by 8

    // ---- CSR build (shared by both layers) ----
    hipMemsetAsync(deg, 0, (size_t)N * sizeof(int), stream);
    hist_deg   <<<eblk, gblk, 0, stream>>>(dsts, E, ET, deg);
    scan_rowptr<<<1,    gblk, 0, stream>>>(deg, rowptr, cursor, N);
    scatter_csr<<<eblk, gblk, 0, stream>>>(srcs, dsts, E, ET, cursor, eidx);

    // ---- split inputs / weights to bf16 hi/lo ----
    split_mat<<<(N * DD + 255) / 256, gblk, 0, stream>>>(x, xs_h, xs_l, N * DD);
    split_wT <<<(1024 * DD + 255) / 256, gblk, 0, stream>>>(Wl1, Wr1, bt1_h, bt1_l, 6);
    split_wT <<<(1024 * HD + 255) / 256, gblk, 0, stream>>>(Wl2, Wr2, bt2_h, bt2_l, 9);

    // ---- layer 1: GATv2Conv(64 -> 64, heads=8, concat) + ELU ----
    gemm_bf16x3<<<gemm_grid, gblk, 0, stream>>>(xs_h, xs_l, bt1_h, bt1_l, xlr, N, DD);
    gat_fused<0><<<nblk, gblk, 0, stream>>>(xlr, att1, b1, rowptr, eidx, N,
                                            nullptr, h1_h, h1_l);

    // ---- layer 2: GATv2Conv(512 -> 64, heads=8, mean) ----
    gemm_bf16x3<<<gemm_grid, gblk, 0, stream>>>(h1_h, h1_l, bt2_h, bt2_l, xlr, N, HD);
    gat_fused<1><<<nblk, gblk, 0, stream>>>(xlr, att2, b2, rowptr, eidx, N,
                                            (float*)d_out, nullptr, nullptr);
}

// Round 12
// 298.113 us; speedup vs baseline: 1.3844x; 1.0309x over previous
//
#include <hip/hip_runtime.h>
#include <hip/hip_fp16.h>
#include <math.h>

#define DD 64      // per-head channels
#define HH 8       // heads
#define HD 512     // HH*DD
#define NC 1024    // combined xl|xr row width

typedef __attribute__((ext_vector_type(8))) short bf16x8;
typedef __attribute__((ext_vector_type(4))) float f32x4;
typedef __attribute__((ext_vector_type(8))) unsigned short ushort8;

// ---------------------------------------------------------------------------
// bf16 split helpers (round-to-nearest-even)
// ---------------------------------------------------------------------------
__device__ __forceinline__ ushort bf16_rne(float f) {
    uint u = __float_as_uint(f);
    u += 0x7fffu + ((u >> 16) & 1u);
    return (ushort)(u >> 16);
}
__device__ __forceinline__ float bf16_tof(ushort h) {
    return __uint_as_float(((uint)h) << 16);
}
__device__ __forceinline__ float h2f(ushort u) {
    __half h; *reinterpret_cast<ushort*>(&h) = u; return __half2float(h);
}

// elementwise fp32 -> (hi, lo) bf16 pair
__global__ __launch_bounds__(256) void split_mat(const float* __restrict__ in,
                                                 ushort* __restrict__ hi,
                                                 ushort* __restrict__ lo, int total)
{
    const int i = blockIdx.x * 256 + threadIdx.x;
    if (i >= total) return;
    const float f = in[i];
    const ushort h = bf16_rne(f);
    hi[i] = h;
    lo[i] = bf16_rne(f - bf16_tof(h));
}

// W0,W1: [K][512] fp32 -> Bt: [1024][K] bf16 hi/lo (transposed, concatenated)
__global__ __launch_bounds__(256) void split_wT(const float* __restrict__ W0,
                                                const float* __restrict__ W1,
                                                ushort* __restrict__ hi,
                                                ushort* __restrict__ lo, int kshift)
{
    const int K = 1 << kshift;
    const int i = blockIdx.x * 256 + threadIdx.x;    // i = c*K + k
    if (i >= 1024 * K) return;
    const int c = i >> kshift, k = i & (K - 1);
    const float* W = (c < 512) ? W0 : W1;
    const float f = W[(size_t)k * 512 + (c & 511)];
    const ushort h = bf16_rne(f);
    hi[i] = h;
    lo[i] = bf16_rne(f - bf16_tof(h));
}

// ---------------------------------------------------------------------------
// bf16x3 split-precision MFMA GEMM; C written as fp16 (feeds the gather).
// Staging via global_load_lds width=16 (HW direct-to-LDS, no VGPR round
// trip). LDS dest is linear (wave-uniform base + lane*16); the XOR bank
// swizzle is applied to the GLOBAL source address instead (m173 pattern):
// lane l fetches k-chunk (l&7)^(l>>3) of its row, so LDS image is
// (row, c) = G(row, c ^ (row&7)) — identical layout to the old store,
// ds_read side unchanged. A-rows clamped (branch-free); C-write masks.
// ---------------------------------------------------------------------------
__global__ __launch_bounds__(256) void gemm_bf16x3(
    const ushort* __restrict__ Ah, const ushort* __restrict__ Al,
    const ushort* __restrict__ Bh, const ushort* __restrict__ Bl,
    __half* __restrict__ C, int M, int K)
{
    __shared__ __align__(16) ushort lAh[128 * 64];
    __shared__ __align__(16) ushort lAl[128 * 64];
    __shared__ __align__(16) ushort lBh[128 * 64];
    __shared__ __align__(16) ushort lBl[128 * 64];

    const int nwg = gridDim.x;                        // 8*MT, divisible by 8
    const int wg  = (blockIdx.x & 7) * (nwg >> 3) + (blockIdx.x >> 3);
    const int ntile = wg & 7, mtile = wg >> 3;
    const int bm = mtile * 128, bn = ntile * 128;

    const int tid  = threadIdx.x;
    const int wid  = tid >> 6;            // 0..3
    const int lane = tid & 63;
    const int wr = wid >> 1, wc = wid & 1;   // 2x2 wave quadrants (64x64)
    const int l15 = lane & 15, g = lane >> 4;

    // staging geometry: each wave-instruction fills 8 rows x 128B linearly;
    // source chunk pre-swizzled so LDS(row,c) = G(row, c^(row&7)).
    const int rsub = lane >> 3;              // row within 8-row group (0..7)
    const int gch  = (lane & 7) ^ rsub;      // pre-swizzled source k-chunk

    f32x4 acc[4][4] = {};

    for (int k0 = 0; k0 < K; k0 += 64) {
        __syncthreads();                   // previous iter's LDS reads done
        #pragma unroll
        for (int q = 0; q < 4; ++q) {
            const int rowb = wid * 32 + q * 8;        // wave-uniform base row
            const int row  = rowb + rsub;
            const size_t ga = (size_t)min(bm + row, M - 1) * K + k0 + gch * 8;
            const size_t gb = (size_t)(bn + row) * K + k0 + gch * 8;
            __builtin_amdgcn_global_load_lds(
                (const __attribute__((address_space(1))) void*)(Ah + ga),
                (__attribute__((address_space(3))) void*)(lAh + rowb * 64), 16, 0, 0);
            __builtin_amdgcn_global_load_lds(
                (const __attribute__((address_space(1))) void*)(Al + ga),
                (__attribute__((address_space(3))) void*)(lAl + rowb * 64), 16, 0, 0);
            __builtin_amdgcn_global_load_lds(
                (const __attribute__((address_space(1))) void*)(Bh + gb),
                (__attribute__((address_space(3))) void*)(lBh + rowb * 64), 16, 0, 0);
            __builtin_amdgcn_global_load_lds(
                (const __attribute__((address_space(1))) void*)(Bl + gb),
                (__attribute__((address_space(3))) void*)(lBl + rowb * 64), 16, 0, 0);
        }
        __syncthreads();                   // drains vmcnt (compiler-emitted)

        #pragma unroll
        for (int kk = 0; kk < 2; ++kk) {
            bf16x8 ah[4], al[4], bh[4], bl[4];
            #pragma unroll
            for (int m = 0; m < 4; ++m) {
                const int row = wr * 64 + m * 16 + l15;
                const int sc  = (kk * 4 + g) ^ (row & 7);
                const int idx = row * 64 + (sc << 3);
                ah[m] = *(const bf16x8*)(lAh + idx);
                al[m] = *(const bf16x8*)(lAl + idx);
            }
            #pragma unroll
            for (int n = 0; n < 4; ++n) {
                const int row = wc * 64 + n * 16 + l15;
                const int sc  = (kk * 4 + g) ^ (row & 7);
                const int idx = row * 64 + (sc << 3);
                bh[n] = *(const bf16x8*)(lBh + idx);
                bl[n] = *(const bf16x8*)(lBl + idx);
            }
            #pragma unroll
            for (int m = 0; m < 4; ++m)
                #pragma unroll
                for (int n = 0; n < 4; ++n) {
                    acc[m][n] = __builtin_amdgcn_mfma_f32_16x16x32_bf16(
                                    ah[m], bh[n], acc[m][n], 0, 0, 0);
                    acc[m][n] = __builtin_amdgcn_mfma_f32_16x16x32_bf16(
                                    ah[m], bl[n], acc[m][n], 0, 0, 0);
                    acc[m][n] = __builtin_amdgcn_mfma_f32_16x16x32_bf16(
                                    al[m], bh[n], acc[m][n], 0, 0, 0);
                }
        }
    }

    #pragma unroll
    for (int m = 0; m < 4; ++m) {
        #pragma unroll
        for (int i = 0; i < 4; ++i) {
            const int row = bm + wr * 64 + m * 16 + g * 4 + i;
            if (row >= M) continue;
            __half* cp = C + (size_t)row * NC + bn + wc * 64 + l15;
            #pragma unroll
            for (int n = 0; n < 4; ++n)
                cp[n * 16] = __float2half_rn(acc[m][n][i]);
        }
    }
}

// ---------------------------------------------------------------------------
// CSR build (per launch; edge list identical for both layers).
// ---------------------------------------------------------------------------
__global__ __launch_bounds__(256) void hist_deg(const int* __restrict__ dsts,
                                                int E, int ET, int* __restrict__ deg)
{
    const int w = blockIdx.x * blockDim.x + threadIdx.x;
    if (w >= ET) return;
    const int d = (w < E) ? dsts[w] : (w - E);   // w >= E: virtual self-loop
    atomicAdd(&deg[d], 1);
}

__global__ __launch_bounds__(256) void scan_rowptr(const int* __restrict__ deg,
                                                   int* __restrict__ rowptr,
                                                   int* __restrict__ cursor, int n)
{
    __shared__ int sums[256];
    const int tid   = threadIdx.x;
    const int chunk = (n + 255) / 256;
    const int lo = min(tid * chunk, n), hi = min(lo + chunk, n);

    int s = 0;
    for (int i = lo; i < hi; ++i) s += deg[i];
    sums[tid] = s;
    __syncthreads();

    for (int off = 1; off < 256; off <<= 1) {
        const int t = (tid >= off) ? sums[tid - off] : 0;
        __syncthreads();
        sums[tid] += t;
        __syncthreads();
    }

    int run = sums[tid] - s;   // exclusive prefix of this chunk
    for (int i = lo; i < hi; ++i) {
        rowptr[i] = run;
        cursor[i] = run;
        run += deg[i];
    }
    if (tid == 255) rowptr[n] = run;   // == ET
}

__global__ __launch_bounds__(256) void scatter_csr(const int* __restrict__ srcs,
                                                   const int* __restrict__ dsts,
                                                   int E, int ET,
                                                   int* __restrict__ cursor,
                                                   int* __restrict__ eidx)
{
    const int w = blockIdx.x * blockDim.x + threadIdx.x;
    if (w >= ET) return;
    int s, d;
    if (w < E) { s = srcs[w]; d = dsts[w]; }
    else       { s = w - E;   d = s; }
    const int pos = atomicAdd(&cursor[d], 1);
    eidx[pos] = s;
}

// ---------------------------------------------------------------------------
// Fused GATv2 edge pipeline + epilogue (unchanged from round 11).
// ONE wave per dst node; lane owns 8 contiguous channels (head = lane>>3).
// ---------------------------------------------------------------------------
__device__ __forceinline__ void edge_step(const ushort8 v,
                                          const float* __restrict__ r,
                                          const float* __restrict__ a,
                                          float* __restrict__ acc, float& den)
{
    float vf[8], s = 0.f;
    #pragma unroll
    for (int j = 0; j < 8; ++j) {
        vf[j] = h2f(v[j]);
        float t = vf[j] + r[j];
        t = t > 0.f ? t : 0.2f * t;          // leaky_relu(0.2)
        s = fmaf(t, a[j], s);
    }
    s += __shfl_xor(s, 1, 64);               // reduce within 8-lane head group
    s += __shfl_xor(s, 2, 64);
    s += __shfl_xor(s, 4, 64);
    const float p = __expf(s);               // logits O(1): no max shift
    den += p;
    #pragma unroll
    for (int j = 0; j < 8; ++j) acc[j] = fmaf(p, vf[j], acc[j]);
}

template<int MODE>
__global__ __launch_bounds__(256) void gat_fused(
    const __half* __restrict__ xlr, const float* __restrict__ att,
    const float* __restrict__ bias, const int* __restrict__ rowptr,
    const int* __restrict__ eidx, int n, float* __restrict__ out,
    ushort* __restrict__ oh, ushort* __restrict__ ol)
{
    const int d    = (blockIdx.x * blockDim.x + threadIdx.x) >> 6;
    const int lane = threadIdx.x & 63;
    if (d >= n) return;

    const int o = lane * 8;                  // channels [o, o+8)

    // xr row (fp16) and att (fp32) -> registers
    float r[8], a[8];
    {
        const ushort8 rv = *(const ushort8*)((const ushort*)xlr + (size_t)d * NC + 512 + o);
        #pragma unroll
        for (int j = 0; j < 8; ++j) r[j] = h2f(rv[j]);
        *(float4*)&a[0] = *(const float4*)(att + o);
        *(float4*)&a[4] = *(const float4*)(att + o + 4);
    }

    float acc[8] = {};
    float den = 0.f;

    const int start = rowptr[d];
    const int end   = rowptr[d + 1];         // deg >= 1 (self-loop)
    const int last  = end - 1;
    const ushort* xb = (const ushort*)xlr;

    ushort8 v0 = *(const ushort8*)(xb + ((size_t)eidx[start] << 10) + o);
    ushort8 v1 = *(const ushort8*)(xb + ((size_t)eidx[min(start + 1, last)] << 10) + o);

    int e = start;
    for (; e + 1 < end; e += 2) {
        const int i2 = min(e + 2, last), i3 = min(e + 3, last);
        const ushort8 n0 = *(const ushort8*)(xb + ((size_t)eidx[i2] << 10) + o);
        const ushort8 n1 = *(const ushort8*)(xb + ((size_t)eidx[i3] << 10) + o);
        edge_step(v0, r, a, acc, den);
        edge_step(v1, r, a, acc, den);
        v0 = n0; v1 = n1;
    }
    if (e < end) edge_step(v0, r, a, acc, den);

    const float inv = 1.f / den;

    if (MODE == 0) {
        // elu(agg + b1), emitted as bf16 hi/lo split for the next GEMM
        float bv[8];
        *(float4*)&bv[0] = *(const float4*)(bias + o);
        *(float4*)&bv[4] = *(const float4*)(bias + o + 4);
        ushort8 hx, lx;
        #pragma unroll
        for (int j = 0; j < 8; ++j) {
            const float u = fmaf(acc[j], inv, bv[j]);
            const float w = u > 0.f ? u : expm1f(u);
            const ushort h = bf16_rne(w);
            hx[j] = h;
            lx[j] = bf16_rne(w - bf16_tof(h));
        }
        *(ushort8*)(oh + (size_t)d * HD + o) = hx;
        *(ushort8*)(ol + (size_t)d * HD + o) = lx;
    } else {
        // mean over 8 heads: reduce across lane bits 3,4,5
        float m[8];
        #pragma unroll
        for (int j = 0; j < 8; ++j) m[j] = acc[j] * inv;
        #pragma unroll
        for (int j = 0; j < 8; ++j) {
            m[j] += __shfl_xor(m[j], 8,  64);
            m[j] += __shfl_xor(m[j], 16, 64);
            m[j] += __shfl_xor(m[j], 32, 64);
        }
        if (lane < 8) {                      // lane covers channels lane*8..+7
            const int c = lane * 8;
            float4 r0, r1;
            r0.x = fmaf(m[0], 0.125f, bias[c + 0]);
            r0.y = fmaf(m[1], 0.125f, bias[c + 1]);
            r0.z = fmaf(m[2], 0.125f, bias[c + 2]);
            r0.w = fmaf(m[3], 0.125f, bias[c + 3]);
            r1.x = fmaf(m[4], 0.125f, bias[c + 4]);
            r1.y = fmaf(m[5], 0.125f, bias[c + 5]);
            r1.z = fmaf(m[6], 0.125f, bias[c + 6]);
            r1.w = fmaf(m[7], 0.125f, bias[c + 7]);
            *(float4*)(out + (size_t)d * DD + c)     = r0;
            *(float4*)(out + (size_t)d * DD + c + 4) = r1;
        }
    }
}

// ---------------------------------------------------------------------------
extern "C" void kernel_launch(void* const* d_in, const int* in_sizes, int n_in,
                              void* d_out, int out_size, void* d_ws, size_t ws_size,
                              hipStream_t stream)
{
    const float* x    = (const float*)d_in[0];
    const int*   ei   = (const int*)  d_in[1];
    const float* Wl1  = (const float*)d_in[2];
    const float* Wr1  = (const float*)d_in[3];
    const float* att1 = (const float*)d_in[4];
    const float* b1   = (const float*)d_in[5];
    const float* Wl2  = (const float*)d_in[6];
    const float* Wr2  = (const float*)d_in[7];
    const float* att2 = (const float*)d_in[8];
    const float* b2   = (const float*)d_in[9];

    const int N  = in_sizes[0] / DD;   // 20000
    const int E  = in_sizes[1] / 2;    // 320000
    const int ET = E + N;              // edges + self-loops

    const int* srcs = ei;
    const int* dsts = ei + E;

    // ---- workspace layout ----
    __half* xlr   = (__half*)d_ws;                      // N*1024 f16 (41 MB)
    ushort* xs_h  = (ushort*)(xlr + (size_t)N * NC);    // N*64
    ushort* xs_l  = xs_h  + (size_t)N * DD;             // N*64
    ushort* h1_h  = xs_l  + (size_t)N * DD;             // N*512
    ushort* h1_l  = h1_h  + (size_t)N * HD;             // N*512
    ushort* bt1_h = h1_l  + (size_t)N * HD;             // 1024*64
    ushort* bt1_l = bt1_h + 1024 * DD;                  // 1024*64
    ushort* bt2_h = bt1_l + 1024 * DD;                  // 1024*512
    ushort* bt2_l = bt2_h + 1024 * HD;                  // 1024*512
    int* rowptr = (int*)(bt2_l + 1024 * HD);            // N+1
    int* deg    = rowptr + (N + 1);                     // N
    int* cursor = deg + N;                              // N
    int* eidx   = cursor + N;                           // ET

    const dim3 gblk(256);
    const int  eblk  = (ET + 255) / 256;
    const int  nblk  = (N + 3) / 4;            // one WAVE per node, 4 nodes/block
    const int  MT    = (N + 127) / 128;        // 157
    const int  gemm_grid = 8 * MT;             // 1256, divisible by 8

    // ---- CSR build (shared by both layers) ----
    hipMemsetAsync(deg, 0, (size_t)N * sizeof(int), stream);
    hist_deg   <<<eblk, gblk, 0, stream>>>(dsts, E, ET, deg);
    scan_rowptr<<<1,    gblk, 0, stream>>>(deg, rowptr, cursor, N);
    scatter_csr<<<eblk, gblk, 0, stream>>>(srcs, dsts, E, ET, cursor, eidx);

    // ---- split inputs / weights to bf16 hi/lo ----
    split_mat<<<(N * DD + 255) / 256, gblk, 0, stream>>>(x, xs_h, xs_l, N * DD);
    split_wT <<<(1024 * DD + 255) / 256, gblk, 0, stream>>>(Wl1, Wr1, bt1_h, bt1_l, 6);
    split_wT <<<(1024 * HD + 255) / 256, gblk, 0, stream>>>(Wl2, Wr2, bt2_h, bt2_l, 9);

    // ---- layer 1: GATv2Conv(64 -> 64, heads=8, concat) + ELU ----
    gemm_bf16x3<<<gemm_grid, gblk, 0, stream>>>(xs_h, xs_l, bt1_h, bt1_l, xlr, N, DD);
    gat_fused<0><<<nblk, gblk, 0, stream>>>(xlr, att1, b1, rowptr, eidx, N,
                                            nullptr, h1_h, h1_l);

    // ---- layer 2: GATv2Conv(512 -> 64, heads=8, mean) ----
    gemm_bf16x3<<<gemm_grid, gblk, 0, stream>>>(h1_h, h1_l, bt2_h, bt2_l, xlr, N, HD);
    gat_fused<1><<<nblk, gblk, 0, stream>>>(xlr, att2, b2, rowptr, eidx, N,
                                            (float*)d_out, nullptr, nullptr);
}